// Round 3
// baseline (325.816 us; speedup 1.0000x reference)
//
#include <hip/hip_runtime.h>

typedef short bf16x8 __attribute__((ext_vector_type(8)));
typedef float f32x4 __attribute__((ext_vector_type(4)));

__device__ __forceinline__ unsigned short f2bf(float f) {
    union { float f; unsigned u; } a; a.f = f;
    unsigned u = a.u;
    u += 0x7fffu + ((u >> 16) & 1u);   // round-to-nearest-even
    return (unsigned short)(u >> 16);
}

__device__ __forceinline__ f32x4 mfma16(bf16x8 a, bf16x8 b, f32x4 c) {
    return __builtin_amdgcn_mfma_f32_16x16x32_bf16(a, b, c, 0, 0, 0);
}

// Expanded transposed weight: wt[n'][k'] = (n'%D==k'%D) ? w[k'/D][n'/D]*scale : 0
// (B' = W (x) I_D, so GEMM K'/N' are the raw interleaved channel indices.)
template<int D, int MUL>
__global__ void expand_w(const float* __restrict__ w, unsigned short* __restrict__ wt,
                         float scale) {
    const int n = blockIdx.x;      // 0..MUL*D-1
    const int k = threadIdx.x;     // 0..MUL*D-1
    float v = 0.0f;
    if (D == 1 || (n % D) == (k % D))
        v = w[(k / D) * MUL + (n / D)] * scale;
    wt[n * (MUL * D) + k] = f2bf(v);
}

// One irrep block for 64 rows: linear bf16 A-stage -> LDS, B' frags from L2,
// direct coalesced C stores. 512 threads = 8 waves; waves split N'.
template<int KP, int OFF, int BASE, bool TAIL>
__device__ __forceinline__ void do_block(const float* __restrict__ xr,
                                         const unsigned short* __restrict__ wb,
                                         float* __restrict__ orow,
                                         unsigned short* As,
                                         int tid, int wv, int lr, int q) {
    constexpr int P     = KP + 8;     // LDS pitch: +16B -> row stride == 4 banks (free 2-way)
    constexpr int KS    = KP / 32;
    constexpr int C8    = KP / 8;
    constexpr int ITERS = KP / 64;    // 64 rows * KP/8 chunks / 512 threads
    constexpr int NTW   = TAIL ? 3 : BASE;

    // ---- stage: 64 rows x KP fp32 (contiguous) -> bf16 LDS, b128 writes ----
    #pragma unroll
    for (int it = 0; it < ITERS; ++it) {
        int idx = tid + it * 512;
        int zl  = idx / C8;                 // const divisor -> mulhi
        int c8  = (idx - zl * C8) * 8;
        const float* p = xr + zl * 960 + OFF + c8;
        f32x4 v0 = *(const f32x4*)p;
        f32x4 v1 = *(const f32x4*)(p + 4);
        bf16x8 sv;
        sv[0] = f2bf(v0[0]); sv[1] = f2bf(v0[1]); sv[2] = f2bf(v0[2]); sv[3] = f2bf(v0[3]);
        sv[4] = f2bf(v1[0]); sv[5] = f2bf(v1[1]); sv[6] = f2bf(v1[2]); sv[7] = f2bf(v1[3]);
        *(bf16x8*)(As + zl * P + c8) = sv;
    }
    __syncthreads();

    int nts[NTW];
    #pragma unroll
    for (int in = 0; in < NTW; ++in)
        nts[in] = (!TAIL || in < 2) ? (wv * BASE + in) : (16 + wv);
    const bool t3 = !TAIL || (wv < 4);      // slot-2 active? (block2: 20 ntiles over 8 waves)

    f32x4 acc[4][NTW];
    #pragma unroll
    for (int mt = 0; mt < 4; ++mt)
        #pragma unroll
        for (int in = 0; in < NTW; ++in)
            acc[mt][in] = (f32x4){0.f, 0.f, 0.f, 0.f};

    #pragma unroll
    for (int ks = 0; ks < KS; ++ks) {
        const int kb = ks * 32 + q * 8;
        bf16x8 b[NTW];
        #pragma unroll
        for (int in = 0; in < NTW; ++in)
            if (in < 2 || t3)
                b[in] = *(const bf16x8*)(wb + (nts[in] * 16 + lr) * KP + kb);
        #pragma unroll
        for (int mt = 0; mt < 4; ++mt) {
            bf16x8 a = *(const bf16x8*)(As + (mt * 16 + lr) * P + kb);
            #pragma unroll
            for (int in = 0; in < NTW; ++in)
                if (in < 2 || t3)
                    acc[mt][in] = mfma16(a, b[in], acc[mt][in]);
        }
    }

    // ---- direct stores: N' == output channel order; 16 lanes -> 64B segments ----
    #pragma unroll
    for (int mt = 0; mt < 4; ++mt)
        #pragma unroll
        for (int in = 0; in < NTW; ++in)
            if (in < 2 || t3) {
                const int col = OFF + nts[in] * 16 + lr;
                #pragma unroll
                for (int j = 0; j < 4; ++j)
                    orow[(mt * 16 + q * 4 + j) * 960 + col] = acc[mt][in][j];
            }
}

__global__ __launch_bounds__(512, 4)
void fused_linear(const float* __restrict__ x, const unsigned short* __restrict__ wt,
                  float* __restrict__ out) {
    __shared__ __align__(16) unsigned short As[64 * 392];   // 50176 B (block1 pitch)
    const int tid  = threadIdx.x;
    const int lane = tid & 63;
    const int wv   = tid >> 6;
    const int lr   = lane & 15;
    const int q    = lane >> 4;
    const long z0  = (long)blockIdx.x * 64;
    const float* xr = x + z0 * 960;
    float* orow = out + z0 * 960;

    do_block<256,   0, 2, false>(xr, wt,          orow, As, tid, wv, lr, q);
    __syncthreads();
    do_block<384, 256, 3, false>(xr, wt +  65536, orow, As, tid, wv, lr, q);
    __syncthreads();
    do_block<320, 640, 2, true >(xr, wt + 212992, orow, As, tid, wv, lr, q);
}

extern "C" void kernel_launch(void* const* d_in, const int* in_sizes, int n_in,
                              void* d_out, int out_size, void* d_ws, size_t ws_size,
                              hipStream_t stream) {
    const float* x  = (const float*)d_in[0];
    const float* w0 = (const float*)d_in[1];
    const float* w1 = (const float*)d_in[2];
    const float* w2 = (const float*)d_in[3];
    float* out = (float*)d_out;
    unsigned short* wt = (unsigned short*)d_ws;  // needs 315392*2 = 630784 B scratch

    const int N = in_sizes[0] / 960;

    expand_w<1, 256><<<256, 256, 0, stream>>>(w0, wt,          0.0625f);
    expand_w<3, 128><<<384, 384, 0, stream>>>(w1, wt +  65536, 0.08838834764831845f);
    expand_w<5,  64><<<320, 320, 0, stream>>>(w2, wt + 212992, 0.125f);

    fused_linear<<<N / 64, 512, 0, stream>>>(x, wt, out);
}